// Round 2
// baseline (369.510 us; speedup 1.0000x reference)
//
#include <hip/hip_runtime.h>

#define NP 256      // P
#define NDD 128     // DD
#define NN 1024     // N
#define NE 250000   // E
#define SB 62       // ceil(NE/4096) blocks per layer for scatter
#define RB 256      // refine blocks: rows 0..2047, 8 per block
#define ESTRIDE 512 // fixed per-segment edge capacity (max real count ~300)

// ---------------------------------------------------------------------------
// K0: prep — transpose weights + (block 46) target-row pipeline:
//   zt = refine(tgt); Qv = Wq@zt+bq; qk = (Wk^T@Qv)/sqrt(DD); s0 = (bk.Qv)/sqrt(DD)
//   cl[l] = Wa1[:, :256]@zt + Wa1[:, 512:528]@le_l + ba1
// ---------------------------------------------------------------------------
__global__ __launch_bounds__(256) void prep_kernel(
    const float* __restrict__ Wr1, const float* __restrict__ Wr2,
    const float* __restrict__ Wa1, const float* __restrict__ Wa2,
    const float* __restrict__ Wv,
    const float* __restrict__ tgt, const float* __restrict__ br1,
    const float* __restrict__ ar1, const float* __restrict__ br2,
    const float* __restrict__ Wq, const float* __restrict__ bq,
    const float* __restrict__ Wk, const float* __restrict__ bk,
    const float* __restrict__ ba1, const float* __restrict__ lemb,
    float* __restrict__ Wr1T, float* __restrict__ Wr2T,
    float* __restrict__ Wa1mT, float* __restrict__ Wa2T, float* __restrict__ WvT,
    float* __restrict__ zt, float* __restrict__ qk, float* __restrict__ s0,
    float* __restrict__ cl)
{
  int b = blockIdx.x, t = threadIdx.x;
  if (b == 46){
    __shared__ float Xs[NP], Hs[NP], Zs[NP], Q[NDD], red[NDD];
    Xs[t] = tgt[t];
    __syncthreads();
    float a = 0.f;
    {
      const float4* w1 = reinterpret_cast<const float4*>(Wr1) + (size_t)t*(NP/4);
      for (int k4 = 0; k4 < NP/4; k4++){
        float4 w = w1[k4];
        float4 x = *reinterpret_cast<const float4*>(&Xs[k4*4]);
        a = fmaf(w.x,x.x,fmaf(w.y,x.y,fmaf(w.z,x.z,fmaf(w.w,x.w,a))));
      }
    }
    float h = a + br1[t];
    float a1 = ar1[0];
    Hs[t] = h >= 0.f ? h : a1*h;
    __syncthreads();
    a = 0.f;
    {
      const float4* w2 = reinterpret_cast<const float4*>(Wr2) + (size_t)t*(NP/4);
      for (int k4 = 0; k4 < NP/4; k4++){
        float4 w = w2[k4];
        float4 x = *reinterpret_cast<const float4*>(&Hs[k4*4]);
        a = fmaf(w.x,x.x,fmaf(w.y,x.y,fmaf(w.z,x.z,fmaf(w.w,x.w,a))));
      }
    }
    float zv = a + br2[t];
    Zs[t] = zv;
    zt[t] = zv;
    __syncthreads();
    if (t < NDD){
      float aq = 0.f;
      const float4* wq = reinterpret_cast<const float4*>(Wq) + (size_t)t*(NP/4);
      for (int k4 = 0; k4 < NP/4; k4++){
        float4 w = wq[k4];
        float4 x = *reinterpret_cast<const float4*>(&Zs[k4*4]);
        aq = fmaf(w.x,x.x,fmaf(w.y,x.y,fmaf(w.z,x.z,fmaf(w.w,x.w,aq))));
      }
      float qv = aq + bq[t];
      Q[t] = qv;
      red[t] = bk[t]*qv;
    }
    __syncthreads();
    const float rs = 0.08838834764831845f;  // 1/sqrt(128)
    if (t < NDD){
      float a2 = 0.f;
      for (int j = 0; j < NDD; j++) a2 = fmaf(Wk[j*NDD + t], Q[j], a2);
      qk[t] = a2 * rs;
    }
    for (int o = 64; o; o >>= 1){
      if (t < o) red[t] += red[t+o];
      __syncthreads();
    }
    if (t == 0) s0[0] = red[0]*rs;
    {
      int l = t >> 7, tt = t & 127;
      const float4* wrow = reinterpret_cast<const float4*>(Wa1 + (size_t)tt*528);
      float ac = 0.f;
      for (int k4 = 0; k4 < 64; k4++){
        float4 w = wrow[k4];
        float4 x = *reinterpret_cast<const float4*>(&Zs[k4*4]);
        ac = fmaf(w.x,x.x,fmaf(w.y,x.y,fmaf(w.z,x.z,fmaf(w.w,x.w,ac))));
      }
      const float* wle = Wa1 + (size_t)tt*528 + 512;
      const float* le = lemb + l*16;
      #pragma unroll
      for (int j2 = 0; j2 < 16; j2++) ac = fmaf(wle[j2], le[j2], ac);
      cl[l*NDD + tt] = ac + ba1[tt];
    }
    return;
  }
  __shared__ float T[64][65];
  const float* src; float* dst;
  int sC, sr0, sc0, dC, dr0, dc0;
  if (b < 16){        int ti=b;    src=Wr1; sC=256; sr0=(ti/4)*64; sc0=(ti%4)*64;
                      dst=Wr1T; dC=256; dr0=sc0; dc0=sr0; }
  else if (b < 32){   int ti=b-16; src=Wr2; sC=256; sr0=(ti/4)*64; sc0=(ti%4)*64;
                      dst=Wr2T; dC=256; dr0=sc0; dc0=sr0; }
  else if (b < 40){   int ti=b-32; src=Wa1; sC=528; sr0=(ti/4)*64; sc0=256+(ti%4)*64;
                      dst=Wa1mT; dC=128; dr0=(ti%4)*64; dc0=sr0; }
  else if (b < 42){   int ti=b-40; src=Wa2; sC=128; sr0=0; sc0=ti*64;
                      dst=Wa2T; dC=64; dr0=sc0; dc0=0; }
  else {              int ti=b-42; src=Wv;  sC=128; sr0=(ti/2)*64; sc0=(ti%2)*64;
                      dst=WvT; dC=128; dr0=sc0; dc0=sr0; }
  #pragma unroll
  for (int j = 0; j < 16; j++){
    int idx = t + j*256;
    int r = idx >> 6, c = idx & 63;
    T[c][r] = src[(size_t)(sr0 + r)*sC + sc0 + c];
  }
  __syncthreads();
  #pragma unroll
  for (int j = 0; j < 16; j++){
    int idx = t + j*256;
    int r = idx >> 6, c = idx & 63;
    dst[(size_t)(dr0 + r)*dC + dc0 + c] = T[r][c];
  }
}

// ---------------------------------------------------------------------------
__device__ __forceinline__ int seg_of(const int* NB, int s){
  if ((unsigned)s < NN && NB[s] == s) return s;
  int lo = 0, hi = NN;
  while (lo < hi){ int mid = (lo+hi)>>1; if (NB[mid] < s) lo = mid+1; else hi = mid; }
  return lo < NN ? lo : NN-1;
}

// ---------------------------------------------------------------------------
// K1: single-pass scatter. No hist, no scan: each segment owns a fixed
// ESTRIDE region; blocks reserve contiguous chunks via one global atomicAdd
// per (block, nonempty segment). cursor ends up holding the per-segment count.
// ---------------------------------------------------------------------------
__global__ __launch_bounds__(1024) void scatter_direct_kernel(
    const int* __restrict__ neighF, const int* __restrict__ srcF,
    const int* __restrict__ dstF, const float* __restrict__ yF,
    const int* __restrict__ neighR, const int* __restrict__ srcR,
    const int* __restrict__ dstR, const float* __restrict__ yR,
    int* __restrict__ cursor, int2* __restrict__ edges)
{
  __shared__ int NB[NN];
  __shared__ int lcnt[NN];
  __shared__ int lbase[NN];
  int bi = blockIdx.x;
  int role = bi >= SB ? 1 : 0;
  int blk = bi - role*SB;
  const int* neigh = role ? neighR : neighF;
  const int* src   = role ? srcR   : srcF;
  const int* dst   = role ? dstR   : dstF;
  const float* yb  = role ? yR     : yF;
  int* cur  = cursor + role*NN;
  int2* ed  = edges  + (size_t)role*NN*ESTRIDE;
  int t = threadIdx.x;
  NB[t] = neigh[t];
  lcnt[t] = 0;
  __syncthreads();

  int segr[4], locr[4]; int2 edr[4];
  #pragma unroll
  for (int i = 0; i < 4; i++){
    int e = blk*4096 + i*1024 + t;
    segr[i] = -1;
    if (e < NE){
      int s = src[e];
      int pos = seg_of(NB, s);
      if (NB[pos] == s){
        segr[i] = pos;
        edr[i]  = make_int2(dst[e], __float_as_int(yb[e]));
        locr[i] = atomicAdd(&lcnt[pos], 1);
      }
    }
  }
  __syncthreads();
  int c = lcnt[t];
  if (c > 0) lbase[t] = atomicAdd(&cur[t], c);
  __syncthreads();
  #pragma unroll
  for (int i = 0; i < 4; i++){
    if (segr[i] >= 0){
      int idx = lbase[segr[i]] + locr[i];
      if (idx < ESTRIDE) ed[(size_t)segr[i]*ESTRIDE + idx] = edr[i];
    }
  }
}

// ---------------------------------------------------------------------------
// K2: fused refine + attn, 256 blocks x 8 rows. z never leaves LDS.
// attn stages 2+3 now use all 4 waves (wave w handles rows w and w+4).
// ---------------------------------------------------------------------------
__global__ __launch_bounds__(256) void refine_attn_kernel(
    const float* __restrict__ formf, const float* __restrict__ rolef,
    const float* __restrict__ Wr1T, const float* __restrict__ br1, const float* __restrict__ ar1,
    const float* __restrict__ Wr2T, const float* __restrict__ br2,
    const float* __restrict__ cl, const float* __restrict__ Wa1mT,
    const float* __restrict__ Wa2T, const float* __restrict__ ba2,
    const float* __restrict__ Wa3, const float* __restrict__ ba3,
    float* __restrict__ attn)
{
  __shared__ float X[8][NP];      // 8 KB
  __shared__ float H[8][NP];      // 8 KB
  __shared__ float H1[8][NDD];    // 4 KB
  const int t = threadIdx.x;
  const int abase = blockIdx.x * 8;        // attn index base: 0..2047
  const int layer = blockIdx.x >> 7;       // uniform per block
  const float* fsrcp = layer ? rolef : formf;
  #pragma unroll
  for (int r = 0; r < 8; r++){
    int nn = (abase + r) & (NN-1);
    X[r][t] = fsrcp[(size_t)nn*NP + t];
  }
  __syncthreads();
  const float a1 = ar1[0];
  float acc[8];
  #pragma unroll
  for (int r = 0; r < 8; r++) acc[r] = 0.f;
  for (int k = 0; k < NP; k += 4){
    float w0 = Wr1T[(k+0)*NP + t];
    float w1 = Wr1T[(k+1)*NP + t];
    float w2 = Wr1T[(k+2)*NP + t];
    float w3 = Wr1T[(k+3)*NP + t];
    #pragma unroll
    for (int r = 0; r < 8; r++){
      float4 x = *reinterpret_cast<const float4*>(&X[r][k]);
      acc[r] = fmaf(w0, x.x, acc[r]);
      acc[r] = fmaf(w1, x.y, acc[r]);
      acc[r] = fmaf(w2, x.z, acc[r]);
      acc[r] = fmaf(w3, x.w, acc[r]);
    }
  }
  const float b1 = br1[t];
  #pragma unroll
  for (int r = 0; r < 8; r++){
    float h = acc[r] + b1;
    H[r][t] = h >= 0.f ? h : a1*h;
  }
  __syncthreads();
  #pragma unroll
  for (int r = 0; r < 8; r++) acc[r] = 0.f;
  for (int k = 0; k < NP; k += 4){
    float w0 = Wr2T[(k+0)*NP + t];
    float w1 = Wr2T[(k+1)*NP + t];
    float w2 = Wr2T[(k+2)*NP + t];
    float w3 = Wr2T[(k+3)*NP + t];
    #pragma unroll
    for (int r = 0; r < 8; r++){
      float4 h4 = *reinterpret_cast<const float4*>(&H[r][k]);
      acc[r] = fmaf(w0, h4.x, acc[r]);
      acc[r] = fmaf(w1, h4.y, acc[r]);
      acc[r] = fmaf(w2, h4.z, acc[r]);
      acc[r] = fmaf(w3, h4.w, acc[r]);
    }
  }
  const float b2 = br2[t];
  #pragma unroll
  for (int r = 0; r < 8; r++) X[r][t] = acc[r] + b2;   // z kept in LDS only
  __syncthreads();

  // attn stage 1: h1 = lrelu(Wa1mid @ z + cl[layer])
  const int tt = t & 127, grp = t >> 7;
  const float c1 = cl[layer*NDD + tt];
  float acc2[4];
  #pragma unroll
  for (int r = 0; r < 4; r++) acc2[r] = 0.f;
  for (int k = 0; k < NP; k += 4){
    float w0 = Wa1mT[(k+0)*NDD + tt];
    float w1 = Wa1mT[(k+1)*NDD + tt];
    float w2 = Wa1mT[(k+2)*NDD + tt];
    float w3 = Wa1mT[(k+3)*NDD + tt];
    #pragma unroll
    for (int r = 0; r < 4; r++){
      float4 x = *reinterpret_cast<const float4*>(&X[grp*4 + r][k]);
      acc2[r] = fmaf(w0, x.x, acc2[r]);
      acc2[r] = fmaf(w1, x.y, acc2[r]);
      acc2[r] = fmaf(w2, x.z, acc2[r]);
      acc2[r] = fmaf(w3, x.w, acc2[r]);
    }
  }
  #pragma unroll
  for (int r = 0; r < 4; r++){
    float h = acc2[r] + c1;
    H1[grp*4 + r][tt] = h >= 0.f ? h : 0.2f*h;
  }
  __syncthreads();
  // attn stages 2+3: wave w = t>>6 handles rows w and w+4; o = t&63.
  {
    const int ro = t >> 6, o = t & 63;
    float a2r[2] = {0.f, 0.f};
    for (int k = 0; k < NDD; k += 4){
      float w0 = Wa2T[(k+0)*64 + o];
      float w1 = Wa2T[(k+1)*64 + o];
      float w2 = Wa2T[(k+2)*64 + o];
      float w3 = Wa2T[(k+3)*64 + o];
      #pragma unroll
      for (int j = 0; j < 2; j++){
        float4 h4 = *reinterpret_cast<const float4*>(&H1[ro + 4*j][k]);
        a2r[j] = fmaf(w0, h4.x, a2r[j]);
        a2r[j] = fmaf(w1, h4.y, a2r[j]);
        a2r[j] = fmaf(w2, h4.z, a2r[j]);
        a2r[j] = fmaf(w3, h4.w, a2r[j]);
      }
    }
    float b2a = ba2[o];
    float w3v = Wa3[o];
    float b3 = ba3[0];
    #pragma unroll
    for (int j = 0; j < 2; j++){
      float h = a2r[j] + b2a;
      h = h >= 0.f ? h : 0.2f*h;
      float p = w3v * h;
      #pragma unroll
      for (int off = 32; off; off >>= 1) p += __shfl_xor(p, off, 64);
      if (o == 0) attn[abase + ro + 4*j] = p + b3;
    }
  }
}

// ---------------------------------------------------------------------------
// K3: per-(layer,segment) softmax-weighted accumulation fused with the Wv
// projection + normalization. Edges live at seg*ESTRIDE; count from cursor.
// ---------------------------------------------------------------------------
__global__ __launch_bounds__(256) void seg_msgs_kernel(
    const float* __restrict__ drug,
    const int2* __restrict__ edges,
    const int* __restrict__ cursor,
    const float* __restrict__ qk, const float* __restrict__ s0p,
    const float* __restrict__ WvT, const float* __restrict__ bv,
    float* __restrict__ msgsf, float* __restrict__ outm)
{
  int b = blockIdx.x;                 // l*1024 + n
  int tid = threadIdx.x;
  int w = tid >> 6, lane = tid & 63, l32 = lane & 31, half = lane >> 5;
  int cnt = min(cursor[b], ESTRIDE);
  int l = b >> 10;
  size_t off = (size_t)(b & (NN-1)) * ESTRIDE;
  const int2* eb = edges + (size_t)l*NN*ESTRIDE;
  float4 q = reinterpret_cast<const float4*>(qk)[l32];
  float s0 = s0p[0];
  int chunk = (cnt + 3) >> 2;
  int start = w*chunk;
  int end = min(start + chunk, cnt);
  float dn = 0.f, cc = 0.f;
  float4 ga = make_float4(0.f,0.f,0.f,0.f);
  for (int i = start; i < end; i += 8){
    int dstp[4]; float yp[4]; bool vp[4];
    #pragma unroll
    for (int p2 = 0; p2 < 4; p2++){
      int idx = i + 2*p2 + half;
      bool v = idx < end;
      int2 e = eb[off + (v ? idx : start)];
      dstp[p2] = e.x; yp[p2] = __int_as_float(e.y); vp[p2] = v;
    }
    float4 dv[4];
    #pragma unroll
    for (int p2 = 0; p2 < 4; p2++){
      dv[p2] = reinterpret_cast<const float4*>(drug + (size_t)dstp[p2]*NDD)[l32];
    }
    #pragma unroll
    for (int p2 = 0; p2 < 4; p2++){
      float4 d = dv[p2];
      float s = fmaf(d.x, q.x, fmaf(d.y, q.y, fmaf(d.z, q.z, d.w*q.w)));
      s += __shfl_xor(s, 16, 64);
      s += __shfl_xor(s,  8, 64);
      s += __shfl_xor(s,  4, 64);
      s += __shfl_xor(s,  2, 64);
      s += __shfl_xor(s,  1, 64);
      float ex = vp[p2] ? __expf(s + s0) : 0.f;
      float wv = ex * (yp[p2] - 6.0f);
      dn += ex; cc += wv;
      ga.x = fmaf(wv, d.x, ga.x);
      ga.y = fmaf(wv, d.y, ga.y);
      ga.z = fmaf(wv, d.z, ga.z);
      ga.w = fmaf(wv, d.w, ga.w);
    }
  }
  __shared__ float4 sG[8][32];
  __shared__ float sD[8], sC[8];
  __shared__ float Grow[NDD];
  __shared__ float part[2][NDD];
  __shared__ float sDen, sCfac;
  int slot = w*2 + half;
  sG[slot][l32] = ga;
  if (l32 == 0){ sD[slot] = dn; sC[slot] = cc; }
  __syncthreads();
  if (tid < NDD){
    int a = tid >> 2, c = tid & 3;
    float v = 0.f;
    #pragma unroll
    for (int k = 0; k < 8; k++)
      v += reinterpret_cast<const float*>(&sG[k][a])[c];
    Grow[tid] = v;
    if (tid == 0){
      float ds = 0.f, cs = 0.f;
      #pragma unroll
      for (int k = 0; k < 8; k++){ ds += sD[k]; cs += sC[k]; }
      sDen = ds; sCfac = cs;
    }
  }
  __syncthreads();
  // Wv GEMV: out[tt] = sum_k Wv[tt][k] * Grow[k]; split k by grp.
  {
    int tt = tid & 127, grp = tid >> 7;
    float acc = 0.f;
    for (int k = grp*64; k < grp*64 + 64; k += 4){
      float w0 = WvT[(k+0)*NDD + tt];
      float w1 = WvT[(k+1)*NDD + tt];
      float w2 = WvT[(k+2)*NDD + tt];
      float w3 = WvT[(k+3)*NDD + tt];
      float4 gv = *reinterpret_cast<const float4*>(&Grow[k]);
      acc = fmaf(w0, gv.x, fmaf(w1, gv.y, fmaf(w2, gv.z, fmaf(w3, gv.w, acc))));
    }
    part[grp][tt] = acc;
  }
  __syncthreads();
  if (tid < NDD){
    float dnm = sDen;
    float v = 0.f;
    if (dnm > 0.f) v = (part[0][tid] + part[1][tid] + bv[tid]*sCfac) / fmaxf(dnm, 1e-30f);
    msgsf[(size_t)b*NDD + tid] = v;
    outm [(size_t)b*NDD + tid] = v;
  }
}

// ---------------------------------------------------------------------------
// K4: fused vprior + final. One 1024-thread block. Unchanged.
// ---------------------------------------------------------------------------
__global__ __launch_bounds__(1024) void vprior_final_kernel(
    const float* __restrict__ attn, const float* __restrict__ msgsf,
    const float* __restrict__ zt,
    const float* __restrict__ Wi1, const float* __restrict__ bi1, const float* __restrict__ ai,
    const float* __restrict__ Wi2, const float* __restrict__ bi2,
    const float* __restrict__ ln_g, const float* __restrict__ ln_b,
    float* __restrict__ zout)
{
  __shared__ float A[2*NN];
  __shared__ float red[1024];
  __shared__ float Pp[8][NDD];
  __shared__ float V[NDD];
  __shared__ float T1[NP];
  __shared__ float red2[NP];
  int t = threadIdx.x;
  A[t] = attn[t]; A[t+1024] = attn[t+1024];
  __syncthreads();
  float mx = fmaxf(A[t], A[t+1024]);
  red[t] = mx; __syncthreads();
  for (int o = 512; o; o >>= 1){ if (t < o) red[t] = fmaxf(red[t], red[t+o]); __syncthreads(); }
  float M = red[0]; __syncthreads();
  float sm = __expf(A[t] - M) + __expf(A[t+1024] - M);
  red[t] = sm; __syncthreads();
  for (int o = 512; o; o >>= 1){ if (t < o) red[t] += red[t+o]; __syncthreads(); }
  float inv = 1.f / red[0]; __syncthreads();
  A[t]      = __expf(A[t]      - M) * inv;
  A[t+1024] = __expf(A[t+1024] - M) * inv;
  __syncthreads();
  int j = t & 127, grp = t >> 7;
  float acc = 0.f;
  int i0 = grp * 256;
  for (int i = i0; i < i0 + 256; i++) acc = fmaf(A[i], msgsf[(size_t)i*NDD + j], acc);
  Pp[grp][j] = acc;
  __syncthreads();
  if (t < NDD){
    float v = 0.f;
    #pragma unroll
    for (int gg = 0; gg < 8; gg++) v += Pp[gg][t];
    V[t] = v;
  }
  __syncthreads();
  float x = 0.f;
  if (t < NP){
    float a1 = 0.f;
    const float4* w1 = reinterpret_cast<const float4*>(Wi1) + t*(NDD/4);
    for (int k4 = 0; k4 < NDD/4; k4++){
      float4 w = w1[k4];
      float4 vv = *reinterpret_cast<const float4*>(&V[k4*4]);
      a1 = fmaf(w.x, vv.x, fmaf(w.y, vv.y, fmaf(w.z, vv.z, fmaf(w.w, vv.w, a1))));
    }
    float h = a1 + bi1[t];
    float a = ai[0];
    T1[t] = h >= 0.f ? h : a*h;
  }
  __syncthreads();
  if (t < NP){
    float a2 = 0.f;
    const float4* w2 = reinterpret_cast<const float4*>(Wi2) + t*(NP/4);
    for (int k4 = 0; k4 < NP/4; k4++){
      float4 w = w2[k4];
      float4 hv = *reinterpret_cast<const float4*>(&T1[k4*4]);
      a2 = fmaf(w.x, hv.x, fmaf(w.y, hv.y, fmaf(w.z, hv.z, fmaf(w.w, hv.w, a2))));
    }
    x = zt[t] + a2 + bi2[t];
    red2[t] = x;
  }
  __syncthreads();
  for (int o = 128; o; o >>= 1){ if (t < o) red2[t] += red2[t+o]; __syncthreads(); }
  float mu = red2[0] * (1.f/256.f); __syncthreads();
  float d = x - mu;
  if (t < NP) red2[t] = d*d;
  __syncthreads();
  for (int o = 128; o; o >>= 1){ if (t < o) red2[t] += red2[t+o]; __syncthreads(); }
  if (t < NP){
    float var = red2[0] * (1.f/256.f);
    float zz = d * rsqrtf(var + 1e-5f) * ln_g[t] + ln_b[t];
    zout[t] = zz;
  }
}

// ---------------------------------------------------------------------------
extern "C" void kernel_launch(void* const* d_in, const int* in_sizes, int n_in,
                              void* d_out, int out_size, void* d_ws, size_t ws_size,
                              hipStream_t stream)
{
  const float* tgt    = (const float*)d_in[0];
  const float* formf  = (const float*)d_in[1];
  const float* rolef  = (const float*)d_in[2];
  const int* fneigh   = (const int*)d_in[3];
  const int* fsrc     = (const int*)d_in[4];
  const int* fdst     = (const int*)d_in[5];
  const float* fy     = (const float*)d_in[6];
  const int* rneigh   = (const int*)d_in[7];
  const int* rsrc     = (const int*)d_in[8];
  const int* rdst     = (const int*)d_in[9];
  const float* ry     = (const float*)d_in[10];
  const float* drug   = (const float*)d_in[11];
  const float* Wr1 = (const float*)d_in[12];
  const float* br1 = (const float*)d_in[13];
  const float* ar1 = (const float*)d_in[14];
  const float* Wr2 = (const float*)d_in[15];
  const float* br2 = (const float*)d_in[16];
  const float* Wq  = (const float*)d_in[17];
  const float* bq  = (const float*)d_in[18];
  const float* Wk  = (const float*)d_in[19];
  const float* bk  = (const float*)d_in[20];
  const float* Wv  = (const float*)d_in[21];
  const float* bv  = (const float*)d_in[22];
  const float* lemb= (const float*)d_in[23];
  const float* Wa1 = (const float*)d_in[24];
  const float* ba1 = (const float*)d_in[25];
  const float* Wa2 = (const float*)d_in[26];
  const float* ba2 = (const float*)d_in[27];
  const float* Wa3 = (const float*)d_in[28];
  const float* ba3 = (const float*)d_in[29];
  const float* Wi1 = (const float*)d_in[30];
  const float* bi1 = (const float*)d_in[31];
  const float* ai  = (const float*)d_in[32];
  const float* Wi2 = (const float*)d_in[33];
  const float* bi2 = (const float*)d_in[34];
  const float* lng = (const float*)d_in[35];
  const float* lnb = (const float*)d_in[36];
  (void)in_sizes; (void)n_in; (void)out_size; (void)ws_size;

  float* ws = (float*)d_ws;
  // ws layout (float offsets), compacted
  float* zt_     = ws + 0;          // 256
  float* qk_     = ws + 256;        // 128
  float* s0_     = ws + 384;        // 1 (padded)
  float* cl_     = ws + 512;        // 256
  float* attn_   = ws + 768;        // 2048
  float* msgsf_  = ws + 2816;       // 262144 -> 264960
  int*   cursor_ = (int*)(ws + 264960);   // 2048 -> 267008
  int2*  edges_  = (int2*)(ws + 267008);  // 2*NN*ESTRIDE int2 = 2097152 fl -> 2364160
  float* Wr1T_   = ws + 2364160;    // 65536
  float* Wr2T_   = ws + 2429696;    // 65536
  float* Wa1mT_  = ws + 2495232;    // 32768
  float* Wa2T_   = ws + 2528000;    // 8192
  float* WvT_    = ws + 2536192;    // 16384

  hipMemsetAsync(cursor_, 0, 2*NN*sizeof(int), stream);

  scatter_direct_kernel<<<2*SB, 1024, 0, stream>>>(fneigh, fsrc, fdst, fy,
                                                   rneigh, rsrc, rdst, ry,
                                                   cursor_, edges_);

  prep_kernel<<<47, 256, 0, stream>>>(Wr1, Wr2, Wa1, Wa2, Wv,
                                      tgt, br1, ar1, br2, Wq, bq, Wk, bk, ba1, lemb,
                                      Wr1T_, Wr2T_, Wa1mT_, Wa2T_, WvT_,
                                      zt_, qk_, s0_, cl_);

  refine_attn_kernel<<<RB, 256, 0, stream>>>(
      formf, rolef, Wr1T_, br1, ar1, Wr2T_, br2,
      cl_, Wa1mT_, Wa2T_, ba2, Wa3, ba3,
      attn_);

  seg_msgs_kernel<<<2*NN, 256, 0, stream>>>(drug, edges_, cursor_, qk_, s0_,
                                            WvT_, bv,
                                            msgsf_, (float*)d_out + NP);

  vprior_final_kernel<<<1, 1024, 0, stream>>>(attn_, msgsf_, zt_,
                                              Wi1, bi1, ai, Wi2, bi2,
                                              lng, lnb, (float*)d_out);
}

// Round 3
// 365.057 us; speedup vs baseline: 1.0122x; 1.0122x over previous
//
#include <hip/hip_runtime.h>

#define NP 256      // P
#define NDD 128     // DD
#define NN 1024     // N
#define NE 250000   // E
#define SB 62       // ceil(NE/4096) blocks per layer for scatter
#define RB 256      // refine blocks: rows 0..2047, 8 per block
#define ESTRIDE 512 // fixed per-segment edge capacity (max real count ~300)

// ---------------------------------------------------------------------------
// K0: prep — transpose weights + (block 46) target-row pipeline + (block 47)
// cursor zeroing (replaces the hipMemsetAsync dispatch).
//   zt = refine(tgt); Qv = Wq@zt+bq; qk = (Wk^T@Qv)/sqrt(DD); s0 = (bk.Qv)/sqrt(DD)
//   cl[l] = Wa1[:, :256]@zt + Wa1[:, 512:528]@le_l + ba1
// ---------------------------------------------------------------------------
__global__ __launch_bounds__(256) void prep_kernel(
    const float* __restrict__ Wr1, const float* __restrict__ Wr2,
    const float* __restrict__ Wa1, const float* __restrict__ Wa2,
    const float* __restrict__ Wv,
    const float* __restrict__ tgt, const float* __restrict__ br1,
    const float* __restrict__ ar1, const float* __restrict__ br2,
    const float* __restrict__ Wq, const float* __restrict__ bq,
    const float* __restrict__ Wk, const float* __restrict__ bk,
    const float* __restrict__ ba1, const float* __restrict__ lemb,
    float* __restrict__ Wr1T, float* __restrict__ Wr2T,
    float* __restrict__ Wa1mT, float* __restrict__ Wa2T, float* __restrict__ WvT,
    float* __restrict__ zt, float* __restrict__ qk, float* __restrict__ s0,
    float* __restrict__ cl, int* __restrict__ cursor)
{
  int b = blockIdx.x, t = threadIdx.x;
  if (b == 47){
    #pragma unroll
    for (int i = 0; i < 2*NN/256; i++) cursor[t + i*256] = 0;
    return;
  }
  if (b == 46){
    __shared__ float Xs[NP], Hs[NP], Zs[NP], Q[NDD], red[NDD];
    Xs[t] = tgt[t];
    __syncthreads();
    float a = 0.f;
    {
      const float4* w1 = reinterpret_cast<const float4*>(Wr1) + (size_t)t*(NP/4);
      for (int k4 = 0; k4 < NP/4; k4++){
        float4 w = w1[k4];
        float4 x = *reinterpret_cast<const float4*>(&Xs[k4*4]);
        a = fmaf(w.x,x.x,fmaf(w.y,x.y,fmaf(w.z,x.z,fmaf(w.w,x.w,a))));
      }
    }
    float h = a + br1[t];
    float a1 = ar1[0];
    Hs[t] = h >= 0.f ? h : a1*h;
    __syncthreads();
    a = 0.f;
    {
      const float4* w2 = reinterpret_cast<const float4*>(Wr2) + (size_t)t*(NP/4);
      for (int k4 = 0; k4 < NP/4; k4++){
        float4 w = w2[k4];
        float4 x = *reinterpret_cast<const float4*>(&Hs[k4*4]);
        a = fmaf(w.x,x.x,fmaf(w.y,x.y,fmaf(w.z,x.z,fmaf(w.w,x.w,a))));
      }
    }
    float zv = a + br2[t];
    Zs[t] = zv;
    zt[t] = zv;
    __syncthreads();
    if (t < NDD){
      float aq = 0.f;
      const float4* wq = reinterpret_cast<const float4*>(Wq) + (size_t)t*(NP/4);
      for (int k4 = 0; k4 < NP/4; k4++){
        float4 w = wq[k4];
        float4 x = *reinterpret_cast<const float4*>(&Zs[k4*4]);
        aq = fmaf(w.x,x.x,fmaf(w.y,x.y,fmaf(w.z,x.z,fmaf(w.w,x.w,aq))));
      }
      float qv = aq + bq[t];
      Q[t] = qv;
      red[t] = bk[t]*qv;
    }
    __syncthreads();
    const float rs = 0.08838834764831845f;  // 1/sqrt(128)
    if (t < NDD){
      float a2 = 0.f;
      for (int j = 0; j < NDD; j++) a2 = fmaf(Wk[j*NDD + t], Q[j], a2);
      qk[t] = a2 * rs;
    }
    for (int o = 64; o; o >>= 1){
      if (t < o) red[t] += red[t+o];
      __syncthreads();
    }
    if (t == 0) s0[0] = red[0]*rs;
    {
      int l = t >> 7, tt = t & 127;
      const float4* wrow = reinterpret_cast<const float4*>(Wa1 + (size_t)tt*528);
      float ac = 0.f;
      for (int k4 = 0; k4 < 64; k4++){
        float4 w = wrow[k4];
        float4 x = *reinterpret_cast<const float4*>(&Zs[k4*4]);
        ac = fmaf(w.x,x.x,fmaf(w.y,x.y,fmaf(w.z,x.z,fmaf(w.w,x.w,ac))));
      }
      const float* wle = Wa1 + (size_t)tt*528 + 512;
      const float* le = lemb + l*16;
      #pragma unroll
      for (int j2 = 0; j2 < 16; j2++) ac = fmaf(wle[j2], le[j2], ac);
      cl[l*NDD + tt] = ac + ba1[tt];
    }
    return;
  }
  __shared__ float T[64][65];
  const float* src; float* dst;
  int sC, sr0, sc0, dC, dr0, dc0;
  if (b < 16){        int ti=b;    src=Wr1; sC=256; sr0=(ti/4)*64; sc0=(ti%4)*64;
                      dst=Wr1T; dC=256; dr0=sc0; dc0=sr0; }
  else if (b < 32){   int ti=b-16; src=Wr2; sC=256; sr0=(ti/4)*64; sc0=(ti%4)*64;
                      dst=Wr2T; dC=256; dr0=sc0; dc0=sr0; }
  else if (b < 40){   int ti=b-32; src=Wa1; sC=528; sr0=(ti/4)*64; sc0=256+(ti%4)*64;
                      dst=Wa1mT; dC=128; dr0=(ti%4)*64; dc0=sr0; }
  else if (b < 42){   int ti=b-40; src=Wa2; sC=128; sr0=0; sc0=ti*64;
                      dst=Wa2T; dC=64; dr0=sc0; dc0=0; }
  else {              int ti=b-42; src=Wv;  sC=128; sr0=(ti/2)*64; sc0=(ti%2)*64;
                      dst=WvT; dC=128; dr0=sc0; dc0=sr0; }
  #pragma unroll
  for (int j = 0; j < 16; j++){
    int idx = t + j*256;
    int r = idx >> 6, c = idx & 63;
    T[c][r] = src[(size_t)(sr0 + r)*sC + sc0 + c];
  }
  __syncthreads();
  #pragma unroll
  for (int j = 0; j < 16; j++){
    int idx = t + j*256;
    int r = idx >> 6, c = idx & 63;
    dst[(size_t)(dr0 + r)*dC + dc0 + c] = T[r][c];
  }
}

// ---------------------------------------------------------------------------
__device__ __forceinline__ int seg_of(const int* NB, int s){
  if ((unsigned)s < NN && NB[s] == s) return s;
  int lo = 0, hi = NN;
  while (lo < hi){ int mid = (lo+hi)>>1; if (NB[mid] < s) lo = mid+1; else hi = mid; }
  return lo < NN ? lo : NN-1;
}

// ---------------------------------------------------------------------------
// K1: single-pass scatter. Each segment owns a fixed ESTRIDE region; blocks
// reserve contiguous chunks via one global atomicAdd per (block, nonempty
// segment). cursor ends up holding the per-segment count.
// ---------------------------------------------------------------------------
__global__ __launch_bounds__(1024) void scatter_direct_kernel(
    const int* __restrict__ neighF, const int* __restrict__ srcF,
    const int* __restrict__ dstF, const float* __restrict__ yF,
    const int* __restrict__ neighR, const int* __restrict__ srcR,
    const int* __restrict__ dstR, const float* __restrict__ yR,
    int* __restrict__ cursor, int2* __restrict__ edges)
{
  __shared__ int NB[NN];
  __shared__ int lcnt[NN];
  __shared__ int lbase[NN];
  int bi = blockIdx.x;
  int role = bi >= SB ? 1 : 0;
  int blk = bi - role*SB;
  const int* neigh = role ? neighR : neighF;
  const int* src   = role ? srcR   : srcF;
  const int* dst   = role ? dstR   : dstF;
  const float* yb  = role ? yR     : yF;
  int* cur  = cursor + role*NN;
  int2* ed  = edges  + (size_t)role*NN*ESTRIDE;
  int t = threadIdx.x;
  NB[t] = neigh[t];
  lcnt[t] = 0;
  __syncthreads();

  int segr[4], locr[4]; int2 edr[4];
  #pragma unroll
  for (int i = 0; i < 4; i++){
    int e = blk*4096 + i*1024 + t;
    segr[i] = -1;
    if (e < NE){
      int s = src[e];
      int pos = seg_of(NB, s);
      if (NB[pos] == s){
        segr[i] = pos;
        edr[i]  = make_int2(dst[e], __float_as_int(yb[e]));
        locr[i] = atomicAdd(&lcnt[pos], 1);
      }
    }
  }
  __syncthreads();
  int c = lcnt[t];
  if (c > 0) lbase[t] = atomicAdd(&cur[t], c);
  __syncthreads();
  #pragma unroll
  for (int i = 0; i < 4; i++){
    if (segr[i] >= 0){
      int idx = lbase[segr[i]] + locr[i];
      if (idx < ESTRIDE) ed[(size_t)segr[i]*ESTRIDE + idx] = edr[i];
    }
  }
}

// ---------------------------------------------------------------------------
// K2: fused refine + attn, 256 blocks x 8 rows. z never leaves LDS.
// ---------------------------------------------------------------------------
__global__ __launch_bounds__(256) void refine_attn_kernel(
    const float* __restrict__ formf, const float* __restrict__ rolef,
    const float* __restrict__ Wr1T, const float* __restrict__ br1, const float* __restrict__ ar1,
    const float* __restrict__ Wr2T, const float* __restrict__ br2,
    const float* __restrict__ cl, const float* __restrict__ Wa1mT,
    const float* __restrict__ Wa2T, const float* __restrict__ ba2,
    const float* __restrict__ Wa3, const float* __restrict__ ba3,
    float* __restrict__ attn)
{
  __shared__ float X[8][NP];      // 8 KB
  __shared__ float H[8][NP];      // 8 KB
  __shared__ float H1[8][NDD];    // 4 KB
  const int t = threadIdx.x;
  const int abase = blockIdx.x * 8;        // attn index base: 0..2047
  const int layer = blockIdx.x >> 7;       // uniform per block
  const float* fsrcp = layer ? rolef : formf;
  #pragma unroll
  for (int r = 0; r < 8; r++){
    int nn = (abase + r) & (NN-1);
    X[r][t] = fsrcp[(size_t)nn*NP + t];
  }
  __syncthreads();
  const float a1 = ar1[0];
  float acc[8];
  #pragma unroll
  for (int r = 0; r < 8; r++) acc[r] = 0.f;
  for (int k = 0; k < NP; k += 4){
    float w0 = Wr1T[(k+0)*NP + t];
    float w1 = Wr1T[(k+1)*NP + t];
    float w2 = Wr1T[(k+2)*NP + t];
    float w3 = Wr1T[(k+3)*NP + t];
    #pragma unroll
    for (int r = 0; r < 8; r++){
      float4 x = *reinterpret_cast<const float4*>(&X[r][k]);
      acc[r] = fmaf(w0, x.x, acc[r]);
      acc[r] = fmaf(w1, x.y, acc[r]);
      acc[r] = fmaf(w2, x.z, acc[r]);
      acc[r] = fmaf(w3, x.w, acc[r]);
    }
  }
  const float b1 = br1[t];
  #pragma unroll
  for (int r = 0; r < 8; r++){
    float h = acc[r] + b1;
    H[r][t] = h >= 0.f ? h : a1*h;
  }
  __syncthreads();
  #pragma unroll
  for (int r = 0; r < 8; r++) acc[r] = 0.f;
  for (int k = 0; k < NP; k += 4){
    float w0 = Wr2T[(k+0)*NP + t];
    float w1 = Wr2T[(k+1)*NP + t];
    float w2 = Wr2T[(k+2)*NP + t];
    float w3 = Wr2T[(k+3)*NP + t];
    #pragma unroll
    for (int r = 0; r < 8; r++){
      float4 h4 = *reinterpret_cast<const float4*>(&H[r][k]);
      acc[r] = fmaf(w0, h4.x, acc[r]);
      acc[r] = fmaf(w1, h4.y, acc[r]);
      acc[r] = fmaf(w2, h4.z, acc[r]);
      acc[r] = fmaf(w3, h4.w, acc[r]);
    }
  }
  const float b2 = br2[t];
  #pragma unroll
  for (int r = 0; r < 8; r++) X[r][t] = acc[r] + b2;   // z kept in LDS only
  __syncthreads();

  // attn stage 1: h1 = lrelu(Wa1mid @ z + cl[layer])
  const int tt = t & 127, grp = t >> 7;
  const float c1 = cl[layer*NDD + tt];
  float acc2[4];
  #pragma unroll
  for (int r = 0; r < 4; r++) acc2[r] = 0.f;
  for (int k = 0; k < NP; k += 4){
    float w0 = Wa1mT[(k+0)*NDD + tt];
    float w1 = Wa1mT[(k+1)*NDD + tt];
    float w2 = Wa1mT[(k+2)*NDD + tt];
    float w3 = Wa1mT[(k+3)*NDD + tt];
    #pragma unroll
    for (int r = 0; r < 4; r++){
      float4 x = *reinterpret_cast<const float4*>(&X[grp*4 + r][k]);
      acc2[r] = fmaf(w0, x.x, acc2[r]);
      acc2[r] = fmaf(w1, x.y, acc2[r]);
      acc2[r] = fmaf(w2, x.z, acc2[r]);
      acc2[r] = fmaf(w3, x.w, acc2[r]);
    }
  }
  #pragma unroll
  for (int r = 0; r < 4; r++){
    float h = acc2[r] + c1;
    H1[grp*4 + r][tt] = h >= 0.f ? h : 0.2f*h;
  }
  __syncthreads();
  // attn stages 2+3: wave w = t>>6 handles rows w and w+4; o = t&63.
  {
    const int ro = t >> 6, o = t & 63;
    float a2r[2] = {0.f, 0.f};
    for (int k = 0; k < NDD; k += 4){
      float w0 = Wa2T[(k+0)*64 + o];
      float w1 = Wa2T[(k+1)*64 + o];
      float w2 = Wa2T[(k+2)*64 + o];
      float w3 = Wa2T[(k+3)*64 + o];
      #pragma unroll
      for (int j = 0; j < 2; j++){
        float4 h4 = *reinterpret_cast<const float4*>(&H1[ro + 4*j][k]);
        a2r[j] = fmaf(w0, h4.x, a2r[j]);
        a2r[j] = fmaf(w1, h4.y, a2r[j]);
        a2r[j] = fmaf(w2, h4.z, a2r[j]);
        a2r[j] = fmaf(w3, h4.w, a2r[j]);
      }
    }
    float b2a = ba2[o];
    float w3v = Wa3[o];
    float b3 = ba3[0];
    #pragma unroll
    for (int j = 0; j < 2; j++){
      float h = a2r[j] + b2a;
      h = h >= 0.f ? h : 0.2f*h;
      float p = w3v * h;
      #pragma unroll
      for (int off = 32; off; off >>= 1) p += __shfl_xor(p, off, 64);
      if (o == 0) attn[abase + ro + 4*j] = p + b3;
    }
  }
}

// ---------------------------------------------------------------------------
// K3: per-(layer,segment) softmax-weighted accumulation fused with the Wv
// projection + normalization. Prefetch depth doubled to 8 edges per half-wave
// iteration (latency-bound kernel: more outstanding gathers per wave).
// Writes only outm (= d_out + NP); vprior reads it back.
// ---------------------------------------------------------------------------
__global__ __launch_bounds__(256) void seg_msgs_kernel(
    const float* __restrict__ drug,
    const int2* __restrict__ edges,
    const int* __restrict__ cursor,
    const float* __restrict__ qk, const float* __restrict__ s0p,
    const float* __restrict__ WvT, const float* __restrict__ bv,
    float* __restrict__ outm)
{
  int b = blockIdx.x;                 // l*1024 + n
  int tid = threadIdx.x;
  int w = tid >> 6, lane = tid & 63, l32 = lane & 31, half = lane >> 5;
  int cnt = min(cursor[b], ESTRIDE);
  int l = b >> 10;
  size_t off = (size_t)(b & (NN-1)) * ESTRIDE;
  const int2* eb = edges + (size_t)l*NN*ESTRIDE + off;
  const float4* dq = reinterpret_cast<const float4*>(drug) + l32;
  float4 q = reinterpret_cast<const float4*>(qk)[l32];
  float s0 = s0p[0];
  int chunk = (cnt + 3) >> 2;
  int start = w*chunk;
  int end = min(start + chunk, cnt);
  float dn = 0.f, cc = 0.f;
  float4 ga = make_float4(0.f,0.f,0.f,0.f);
  for (int i = start; i < end; i += 16){
    int dstp[8]; float yp[8]; bool vp[8];
    #pragma unroll
    for (int p2 = 0; p2 < 8; p2++){
      int idx = i + 2*p2 + half;
      bool v = idx < end;
      int2 e = eb[v ? idx : start];
      dstp[p2] = e.x; yp[p2] = __int_as_float(e.y); vp[p2] = v;
    }
    float4 dv[8];
    #pragma unroll
    for (int p2 = 0; p2 < 8; p2++){
      dv[p2] = dq[(size_t)dstp[p2]*(NDD/4)];
    }
    #pragma unroll
    for (int p2 = 0; p2 < 8; p2++){
      float4 d = dv[p2];
      float s = fmaf(d.x, q.x, fmaf(d.y, q.y, fmaf(d.z, q.z, d.w*q.w)));
      s += __shfl_xor(s, 16, 64);
      s += __shfl_xor(s,  8, 64);
      s += __shfl_xor(s,  4, 64);
      s += __shfl_xor(s,  2, 64);
      s += __shfl_xor(s,  1, 64);
      float ex = vp[p2] ? __expf(s + s0) : 0.f;
      float wv = ex * (yp[p2] - 6.0f);
      dn += ex; cc += wv;
      ga.x = fmaf(wv, d.x, ga.x);
      ga.y = fmaf(wv, d.y, ga.y);
      ga.z = fmaf(wv, d.z, ga.z);
      ga.w = fmaf(wv, d.w, ga.w);
    }
  }
  __shared__ float4 sG[8][32];
  __shared__ float sD[8], sC[8];
  __shared__ float Grow[NDD];
  __shared__ float part[2][NDD];
  __shared__ float sDen, sCfac;
  int slot = w*2 + half;
  sG[slot][l32] = ga;
  if (l32 == 0){ sD[slot] = dn; sC[slot] = cc; }
  __syncthreads();
  if (tid < NDD){
    int a = tid >> 2, c = tid & 3;
    float v = 0.f;
    #pragma unroll
    for (int k = 0; k < 8; k++)
      v += reinterpret_cast<const float*>(&sG[k][a])[c];
    Grow[tid] = v;
    if (tid == 0){
      float ds = 0.f, cs = 0.f;
      #pragma unroll
      for (int k = 0; k < 8; k++){ ds += sD[k]; cs += sC[k]; }
      sDen = ds; sCfac = cs;
    }
  }
  __syncthreads();
  // Wv GEMV: out[tt] = sum_k Wv[tt][k] * Grow[k]; split k by grp.
  {
    int tt = tid & 127, grp = tid >> 7;
    float acc = 0.f;
    for (int k = grp*64; k < grp*64 + 64; k += 4){
      float w0 = WvT[(k+0)*NDD + tt];
      float w1 = WvT[(k+1)*NDD + tt];
      float w2 = WvT[(k+2)*NDD + tt];
      float w3 = WvT[(k+3)*NDD + tt];
      float4 gv = *reinterpret_cast<const float4*>(&Grow[k]);
      acc = fmaf(w0, gv.x, fmaf(w1, gv.y, fmaf(w2, gv.z, fmaf(w3, gv.w, acc))));
    }
    part[grp][tt] = acc;
  }
  __syncthreads();
  if (tid < NDD){
    float dnm = sDen;
    float v = 0.f;
    if (dnm > 0.f) v = (part[0][tid] + part[1][tid] + bv[tid]*sCfac) / fmaxf(dnm, 1e-30f);
    outm[(size_t)b*NDD + tid] = v;
  }
}

// ---------------------------------------------------------------------------
// K4: fused vprior + final. One 1024-thread block. Reads msgs from outm.
// ---------------------------------------------------------------------------
__global__ __launch_bounds__(1024) void vprior_final_kernel(
    const float* __restrict__ attn, const float* __restrict__ msgsf,
    const float* __restrict__ zt,
    const float* __restrict__ Wi1, const float* __restrict__ bi1, const float* __restrict__ ai,
    const float* __restrict__ Wi2, const float* __restrict__ bi2,
    const float* __restrict__ ln_g, const float* __restrict__ ln_b,
    float* __restrict__ zout)
{
  __shared__ float A[2*NN];
  __shared__ float red[1024];
  __shared__ float Pp[8][NDD];
  __shared__ float V[NDD];
  __shared__ float T1[NP];
  __shared__ float red2[NP];
  int t = threadIdx.x;
  A[t] = attn[t]; A[t+1024] = attn[t+1024];
  __syncthreads();
  float mx = fmaxf(A[t], A[t+1024]);
  red[t] = mx; __syncthreads();
  for (int o = 512; o; o >>= 1){ if (t < o) red[t] = fmaxf(red[t], red[t+o]); __syncthreads(); }
  float M = red[0]; __syncthreads();
  float sm = __expf(A[t] - M) + __expf(A[t+1024] - M);
  red[t] = sm; __syncthreads();
  for (int o = 512; o; o >>= 1){ if (t < o) red[t] += red[t+o]; __syncthreads(); }
  float inv = 1.f / red[0]; __syncthreads();
  A[t]      = __expf(A[t]      - M) * inv;
  A[t+1024] = __expf(A[t+1024] - M) * inv;
  __syncthreads();
  int j = t & 127, grp = t >> 7;
  float acc = 0.f;
  int i0 = grp * 256;
  for (int i = i0; i < i0 + 256; i++) acc = fmaf(A[i], msgsf[(size_t)i*NDD + j], acc);
  Pp[grp][j] = acc;
  __syncthreads();
  if (t < NDD){
    float v = 0.f;
    #pragma unroll
    for (int gg = 0; gg < 8; gg++) v += Pp[gg][t];
    V[t] = v;
  }
  __syncthreads();
  float x = 0.f;
  if (t < NP){
    float a1 = 0.f;
    const float4* w1 = reinterpret_cast<const float4*>(Wi1) + t*(NDD/4);
    for (int k4 = 0; k4 < NDD/4; k4++){
      float4 w = w1[k4];
      float4 vv = *reinterpret_cast<const float4*>(&V[k4*4]);
      a1 = fmaf(w.x, vv.x, fmaf(w.y, vv.y, fmaf(w.z, vv.z, fmaf(w.w, vv.w, a1))));
    }
    float h = a1 + bi1[t];
    float a = ai[0];
    T1[t] = h >= 0.f ? h : a*h;
  }
  __syncthreads();
  if (t < NP){
    float a2 = 0.f;
    const float4* w2 = reinterpret_cast<const float4*>(Wi2) + t*(NP/4);
    for (int k4 = 0; k4 < NP/4; k4++){
      float4 w = w2[k4];
      float4 hv = *reinterpret_cast<const float4*>(&T1[k4*4]);
      a2 = fmaf(w.x, hv.x, fmaf(w.y, hv.y, fmaf(w.z, hv.z, fmaf(w.w, hv.w, a2))));
    }
    x = zt[t] + a2 + bi2[t];
    red2[t] = x;
  }
  __syncthreads();
  for (int o = 128; o; o >>= 1){ if (t < o) red2[t] += red2[t+o]; __syncthreads(); }
  float mu = red2[0] * (1.f/256.f); __syncthreads();
  float d = x - mu;
  if (t < NP) red2[t] = d*d;
  __syncthreads();
  for (int o = 128; o; o >>= 1){ if (t < o) red2[t] += red2[t+o]; __syncthreads(); }
  if (t < NP){
    float var = red2[0] * (1.f/256.f);
    float zz = d * rsqrtf(var + 1e-5f) * ln_g[t] + ln_b[t];
    zout[t] = zz;
  }
}

// ---------------------------------------------------------------------------
extern "C" void kernel_launch(void* const* d_in, const int* in_sizes, int n_in,
                              void* d_out, int out_size, void* d_ws, size_t ws_size,
                              hipStream_t stream)
{
  const float* tgt    = (const float*)d_in[0];
  const float* formf  = (const float*)d_in[1];
  const float* rolef  = (const float*)d_in[2];
  const int* fneigh   = (const int*)d_in[3];
  const int* fsrc     = (const int*)d_in[4];
  const int* fdst     = (const int*)d_in[5];
  const float* fy     = (const float*)d_in[6];
  const int* rneigh   = (const int*)d_in[7];
  const int* rsrc     = (const int*)d_in[8];
  const int* rdst     = (const int*)d_in[9];
  const float* ry     = (const float*)d_in[10];
  const float* drug   = (const float*)d_in[11];
  const float* Wr1 = (const float*)d_in[12];
  const float* br1 = (const float*)d_in[13];
  const float* ar1 = (const float*)d_in[14];
  const float* Wr2 = (const float*)d_in[15];
  const float* br2 = (const float*)d_in[16];
  const float* Wq  = (const float*)d_in[17];
  const float* bq  = (const float*)d_in[18];
  const float* Wk  = (const float*)d_in[19];
  const float* bk  = (const float*)d_in[20];
  const float* Wv  = (const float*)d_in[21];
  const float* bv  = (const float*)d_in[22];
  const float* lemb= (const float*)d_in[23];
  const float* Wa1 = (const float*)d_in[24];
  const float* ba1 = (const float*)d_in[25];
  const float* Wa2 = (const float*)d_in[26];
  const float* ba2 = (const float*)d_in[27];
  const float* Wa3 = (const float*)d_in[28];
  const float* ba3 = (const float*)d_in[29];
  const float* Wi1 = (const float*)d_in[30];
  const float* bi1 = (const float*)d_in[31];
  const float* ai  = (const float*)d_in[32];
  const float* Wi2 = (const float*)d_in[33];
  const float* bi2 = (const float*)d_in[34];
  const float* lng = (const float*)d_in[35];
  const float* lnb = (const float*)d_in[36];
  (void)in_sizes; (void)n_in; (void)out_size; (void)ws_size;

  float* ws = (float*)d_ws;
  // ws layout (float offsets), compacted
  float* zt_     = ws + 0;          // 256
  float* qk_     = ws + 256;        // 128
  float* s0_     = ws + 384;        // 1 (padded)
  float* cl_     = ws + 512;        // 256
  float* attn_   = ws + 768;        // 2048
  int*   cursor_ = (int*)(ws + 2816);     // 2048 -> 4864
  int2*  edges_  = (int2*)(ws + 4864);    // 2*NN*ESTRIDE int2 = 2097152 fl
  float* Wr1T_   = ws + 2102016;    // 65536
  float* Wr2T_   = ws + 2167552;    // 65536
  float* Wa1mT_  = ws + 2233088;    // 32768
  float* Wa2T_   = ws + 2265856;    // 8192
  float* WvT_    = ws + 2274048;    // 16384

  float* outm_ = (float*)d_out + NP;      // [2N][DD] messages (also vprior input)

  prep_kernel<<<48, 256, 0, stream>>>(Wr1, Wr2, Wa1, Wa2, Wv,
                                      tgt, br1, ar1, br2, Wq, bq, Wk, bk, ba1, lemb,
                                      Wr1T_, Wr2T_, Wa1mT_, Wa2T_, WvT_,
                                      zt_, qk_, s0_, cl_, cursor_);

  scatter_direct_kernel<<<2*SB, 1024, 0, stream>>>(fneigh, fsrc, fdst, fy,
                                                   rneigh, rsrc, rdst, ry,
                                                   cursor_, edges_);

  refine_attn_kernel<<<RB, 256, 0, stream>>>(
      formf, rolef, Wr1T_, br1, ar1, Wr2T_, br2,
      cl_, Wa1mT_, Wa2T_, ba2, Wa3, ba3,
      attn_);

  seg_msgs_kernel<<<2*NN, 256, 0, stream>>>(drug, edges_, cursor_, qk_, s0_,
                                            WvT_, bv, outm_);

  vprior_final_kernel<<<1, 1024, 0, stream>>>(attn_, outm_, zt_,
                                              Wi1, bi1, ai, Wi2, bi2,
                                              lng, lnb, (float*)d_out);
}